// Round 4
// baseline (488.794 us; speedup 1.0000x reference)
//
#include <hip/hip_runtime.h>
#include <hip/hip_bf16.h>

#define DIM 192
#define HEADS 6
#define HD 32
#define NTOK 64
#define BATCH 2048
#define CPBH 512
#define TBL 343
#define NW 64

typedef unsigned int u32;
typedef __attribute__((ext_vector_type(8))) short b16x8;
typedef __attribute__((ext_vector_type(4))) float f32x4;

__device__ __forceinline__ unsigned short f2bf(float f) {
  union { __hip_bfloat16 h; unsigned short s; } cv;
  cv.h = __float2bfloat16(f);
  return cv.s;
}
__device__ __forceinline__ u32 pack2(float a, float b) {
  return (u32)f2bf(a) | ((u32)f2bf(b) << 16);
}
union FragU { u32 u[4]; b16x8 s; uint4 q; };

__device__ __forceinline__ b16x8 ld_frag_g(const u32* p) {   // 16B-aligned global/LDS
  FragU f; f.q = *(const uint4*)p; return f.s;
}
__device__ __forceinline__ b16x8 ld_frag_b32(const u32* p) { // 4B-safe LDS
  FragU f; f.u[0] = p[0]; f.u[1] = p[1]; f.u[2] = p[2]; f.u[3] = p[3]; return f.s;
}

// ---------- CPB MLP: one wave per table row ----------
__global__ __launch_bounds__(64) void k_cpb1(
    const float* __restrict__ rpb, const float* __restrict__ w1,
    const float* __restrict__ b1, const float* __restrict__ w2,
    float* __restrict__ tab) {
  int t = blockIdx.x, lane = threadIdx.x;
  float r0 = rpb[t*3], r1 = rpb[t*3+1], r2 = rpb[t*3+2];
  float a[HEADS];
  #pragma unroll
  for (int h = 0; h < HEADS; ++h) a[h] = 0.f;
  #pragma unroll
  for (int kk = 0; kk < 8; ++kk) {
    int k = lane * 8 + kk;
    float hv = fmaf(r0, w1[k*3], fmaf(r1, w1[k*3+1], fmaf(r2, w1[k*3+2], b1[k])));
    hv = fmaxf(hv, 0.f);
    #pragma unroll
    for (int h = 0; h < HEADS; ++h) a[h] = fmaf(hv, w2[h*CPBH + k], a[h]);
  }
  #pragma unroll
  for (int h = 0; h < HEADS; ++h) {
    a[h] += __shfl_xor(a[h], 1);  a[h] += __shfl_xor(a[h], 2);
    a[h] += __shfl_xor(a[h], 4);  a[h] += __shfl_xor(a[h], 8);
    a[h] += __shfl_xor(a[h], 16); a[h] += __shfl_xor(a[h], 32);
  }
  if (lane == 0) {
    #pragma unroll
    for (int h = 0; h < HEADS; ++h) tab[t*HEADS + h] = a[h];
  }
}

// ---------- bias+mask, TRANSPOSED (nw, h, col, row) fp32 ----------
__global__ void k_bmt(const float* __restrict__ tab, const int* __restrict__ ridx,
                      const float* __restrict__ mask, float* __restrict__ bmt) {
  int idx = blockIdx.x * blockDim.x + threadIdx.x;
  if (idx >= NW * HEADS * 4096) return;
  int cr = idx & 4095;
  int col = cr >> 6, row = cr & 63;
  int h = (idx >> 12) % HEADS;
  int nw = idx / (HEADS * 4096);
  int ij = row * 64 + col;
  float v = tab[ridx[ij] * HEADS + h];
  bmt[idx] = 16.f / (1.f + __expf(-v)) + mask[nw * 4096 + ij];
}

// ---------- one-time fp32 -> bf16 weight conversion ----------
__global__ void k_wcvt(const float* __restrict__ qkvw, const float* __restrict__ pw,
                       u32* __restrict__ wq, u32* __restrict__ wp) {
  int i = blockIdx.x * blockDim.x + threadIdx.x;
  if (i < 55296) {
    wq[i] = pack2(qkvw[2*i], qkvw[2*i+1]);
  } else if (i < 55296 + 18432) {
    int j = i - 55296;
    wp[j] = pack2(pw[2*j], pw[2*j+1]);
  }
}

// ---------- mega kernel: qkv + attention + proj, one block per window ----------
// Region A (u32[13056]): per head h at h*2176: q (64x17), k (64x17); P (64x33)
//   overlays q+k after their frags are in registers (per-wave safe).
//   aol (64x100) overlays regA[0..6400) after barrier.
// Region B (u32[6912]): v per head at h*1152: 32 rows (d) x 36 stride (token pairs).
__global__ __launch_bounds__(384, 3) void k_mega(
    const float* __restrict__ x, const u32* __restrict__ wq,
    const float* __restrict__ qkvb, const float* __restrict__ bmt,
    const float* __restrict__ ls, const u32* __restrict__ wp,
    const float* __restrict__ pb, float* __restrict__ out) {
  __shared__ alignas(16) u32 regA[13056];
  __shared__ alignas(16) u32 regB[6912];
  const int tid = threadIdx.x;
  const int b = blockIdx.x;
  const int h = tid >> 6;
  const int lane = tid & 63;
  const int m = lane & 15, qd = lane >> 4;
  u32* qh = regA + h * 2176;
  u32* kh = qh + 1088;
  u32* Ph = qh;                 // stride 33, overlays q+k (2112 <= 2176)
  u32* vh = regB + h * 1152;    // stride 36
  u32* aol = regA;              // stride 100, after barrier

  // ================= phase 1: QKV for head h =================
  const float* xw = x + (size_t)b * (NTOK * DIM);
  #pragma unroll 1
  for (int tp = 0; tp < 2; ++tp) {
    // x B-frags for tokens (tp*2+tt)*16+m, dims qd*8.. per ks
    b16x8 xf[2][6];
    #pragma unroll
    for (int tt = 0; tt < 2; ++tt) {
      const float* xr = xw + ((tp*2 + tt)*16 + m) * DIM + qd * 8;
      #pragma unroll
      for (int ks = 0; ks < 6; ++ks) {
        float4 f0 = *(const float4*)(xr + ks*32);
        float4 f1 = *(const float4*)(xr + ks*32 + 4);
        FragU fu;
        fu.u[0] = pack2(f0.x, f0.y); fu.u[1] = pack2(f0.z, f0.w);
        fu.u[2] = pack2(f1.x, f1.y); fu.u[3] = pack2(f1.z, f1.w);
        xf[tt][ks] = fu.s;
      }
    }
    #pragma unroll 1
    for (int sel = 0; sel < 3; ++sel) {
      f32x4 acc[2][2];   // [half][tt]
      float bv[2][4];
      #pragma unroll
      for (int half = 0; half < 2; ++half) {
        b16x8 af[6];
        const u32* wrow = wq + (size_t)(sel*192 + h*32 + half*16 + m) * 96;
        #pragma unroll
        for (int ks = 0; ks < 6; ++ks) af[ks] = ld_frag_g(wrow + ks*16 + qd*4);
        #pragma unroll
        for (int r = 0; r < 4; ++r) bv[half][r] = qkvb[sel*192 + h*32 + half*16 + qd*4 + r];
        acc[half][0] = (f32x4){0.f,0.f,0.f,0.f};
        acc[half][1] = (f32x4){0.f,0.f,0.f,0.f};
        #pragma unroll
        for (int ks = 0; ks < 6; ++ks) {
          acc[half][0] = __builtin_amdgcn_mfma_f32_16x16x32_bf16(af[ks], xf[0][ks], acc[half][0], 0,0,0);
          acc[half][1] = __builtin_amdgcn_mfma_f32_16x16x32_bf16(af[ks], xf[1][ks], acc[half][1], 0,0,0);
        }
      }
      #pragma unroll
      for (int tt = 0; tt < 2; ++tt) {
        const int t = tp*2 + tt;
        f32x4 a0 = acc[0][tt], a1 = acc[1][tt];
        #pragma unroll
        for (int r = 0; r < 4; ++r) { a0[r] += bv[0][r]; a1[r] += bv[1][r]; }
        if (sel < 2) {
          float ss = 0.f;
          #pragma unroll
          for (int r = 0; r < 4; ++r) ss = fmaf(a0[r], a0[r], fmaf(a1[r], a1[r], ss));
          ss += __shfl_xor(ss, 16);
          ss += __shfl_xor(ss, 32);
          float inv = 1.f / fmaxf(sqrtf(ss), 1e-12f);
          #pragma unroll
          for (int r = 0; r < 4; ++r) { a0[r] *= inv; a1[r] *= inv; }
          u32* dst = (sel == 0) ? qh : kh;
          u32* o = dst + (t*16 + m) * 17;
          o[qd*2]     = pack2(a0[0], a0[1]);
          o[qd*2 + 1] = pack2(a0[2], a0[3]);
          o[8 + qd*2]     = pack2(a1[0], a1[1]);
          o[8 + qd*2 + 1] = pack2(a1[2], a1[3]);
        } else {
          float p0[8];
          #pragma unroll
          for (int r = 0; r < 4; ++r) { p0[r] = a0[r]; p0[4+r] = a1[r]; }
          float pr[8];
          #pragma unroll
          for (int e = 0; e < 8; ++e) pr[e] = __shfl_xor(p0[e], 1);
          if ((m & 1) == 0) {
            #pragma unroll
            for (int e = 0; e < 8; ++e) {
              int d = (e >> 2)*16 + qd*4 + (e & 3);
              vh[d*36 + t*8 + (m >> 1)] = pack2(p0[e], pr[e]);
            }
          }
        }
      }
    }
  }
  // per-wave: no barrier needed (q/k/v/P of head h touched only by wave h)

  // ================= S = qn knT * scale + bias+mask =================
  b16x8 qfr[4], kfr[4];
  #pragma unroll
  for (int mt = 0; mt < 4; ++mt) qfr[mt] = ld_frag_b32(qh + (mt*16 + m)*17 + qd*4);
  #pragma unroll
  for (int ct = 0; ct < 4; ++ct) kfr[ct] = ld_frag_b32(kh + (ct*16 + m)*17 + qd*4);

  f32x4 s[4][4];
  #pragma unroll
  for (int mt = 0; mt < 4; ++mt)
    #pragma unroll
    for (int ct = 0; ct < 4; ++ct) {
      f32x4 z = {0.f,0.f,0.f,0.f};
      s[mt][ct] = __builtin_amdgcn_mfma_f32_16x16x32_bf16(qfr[mt], kfr[ct], z, 0,0,0);
    }

  const float sc = __expf(fminf(ls[h], 4.60517019f));
  const float* bmp = bmt + ((size_t)(b & 63) * HEADS + h) * 4096;
  #pragma unroll
  for (int mt = 0; mt < 4; ++mt)
    #pragma unroll
    for (int ct = 0; ct < 4; ++ct) {
      float4 bb = *(const float4*)(bmp + (ct*16 + m)*64 + mt*16 + qd*4);
      s[mt][ct][0] = fmaf(s[mt][ct][0], sc, bb.x);
      s[mt][ct][1] = fmaf(s[mt][ct][1], sc, bb.y);
      s[mt][ct][2] = fmaf(s[mt][ct][2], sc, bb.z);
      s[mt][ct][3] = fmaf(s[mt][ct][3], sc, bb.w);
    }

  // ================= softmax + P to LDS (overlay q/k) =================
  float rinv[4][4];
  #pragma unroll
  for (int mt = 0; mt < 4; ++mt) {
    #pragma unroll
    for (int r = 0; r < 4; ++r) {
      float mm = s[mt][0][r];
      #pragma unroll
      for (int ct = 1; ct < 4; ++ct) mm = fmaxf(mm, s[mt][ct][r]);
      mm = fmaxf(mm, __shfl_xor(mm, 1)); mm = fmaxf(mm, __shfl_xor(mm, 2));
      mm = fmaxf(mm, __shfl_xor(mm, 4)); mm = fmaxf(mm, __shfl_xor(mm, 8));
      float l = 0.f;
      #pragma unroll
      for (int ct = 0; ct < 4; ++ct) { s[mt][ct][r] = __expf(s[mt][ct][r] - mm); l += s[mt][ct][r]; }
      l += __shfl_xor(l, 1); l += __shfl_xor(l, 2);
      l += __shfl_xor(l, 4); l += __shfl_xor(l, 8);
      rinv[mt][r] = 1.f / l;
      int row = mt*16 + qd*4 + r;
      #pragma unroll
      for (int ct = 0; ct < 4; ++ct) {
        float pv = s[mt][ct][r];
        float pn = __shfl_xor(pv, 1);
        if ((m & 1) == 0) Ph[row*33 + ct*8 + (m >> 1)] = pack2(pv, pn);
      }
    }
  }

  // ================= PV (all per-wave) =================
  b16x8 vfr[2][2];
  #pragma unroll
  for (int nt = 0; nt < 2; ++nt)
    #pragma unroll
    for (int ks = 0; ks < 2; ++ks)
      vfr[nt][ks] = ld_frag_g(vh + (nt*16 + m)*36 + ks*16 + qd*4);
  f32x4 o[4][2];
  #pragma unroll
  for (int mt = 0; mt < 4; ++mt) {
    b16x8 pa0 = ld_frag_b32(Ph + (mt*16 + m)*33 + qd*4);
    b16x8 pa1 = ld_frag_b32(Ph + (mt*16 + m)*33 + 16 + qd*4);
    #pragma unroll
    for (int nt = 0; nt < 2; ++nt) {
      f32x4 acc = {0.f,0.f,0.f,0.f};
      acc = __builtin_amdgcn_mfma_f32_16x16x32_bf16(pa0, vfr[nt][0], acc, 0,0,0);
      acc = __builtin_amdgcn_mfma_f32_16x16x32_bf16(pa1, vfr[nt][1], acc, 0,0,0);
      o[mt][nt] = acc;
    }
  }

  __syncthreads();   // all waves done reading P/v before aol overlays region A

  #pragma unroll
  for (int mt = 0; mt < 4; ++mt)
    #pragma unroll
    for (int nt = 0; nt < 2; ++nt) {
      #pragma unroll
      for (int r = 0; r < 4; ++r) {
        float val = o[mt][nt][r] * rinv[mt][r];
        float pn = __shfl_xor(val, 1);
        if ((m & 1) == 0) {
          int row = mt*16 + qd*4 + r;
          aol[row*100 + h*16 + nt*8 + (m >> 1)] = pack2(val, pn);
        }
      }
    }

  __syncthreads();   // aol complete before proj reads

  // ================= projection: wave h -> out cols h*32..h*32+31 =================
  b16x8 afp[2][6];
  float bvp[2][4];
  #pragma unroll
  for (int jj = 0; jj < 2; ++jj) {
    const u32* wrow = wp + (size_t)((h*2 + jj)*16 + m) * 96;
    #pragma unroll
    for (int ks = 0; ks < 6; ++ks) afp[jj][ks] = ld_frag_g(wrow + ks*16 + qd*4);
    #pragma unroll
    for (int r = 0; r < 4; ++r) bvp[jj][r] = pb[(h*2 + jj)*16 + qd*4 + r];
  }
  #pragma unroll 1
  for (int t = 0; t < 4; ++t) {
    f32x4 acc0 = {0.f,0.f,0.f,0.f}, acc1 = {0.f,0.f,0.f,0.f};
    #pragma unroll
    for (int ks = 0; ks < 6; ++ks) {
      b16x8 bfr = ld_frag_g(aol + (t*16 + m)*100 + ks*16 + qd*4);
      acc0 = __builtin_amdgcn_mfma_f32_16x16x32_bf16(afp[0][ks], bfr, acc0, 0,0,0);
      acc1 = __builtin_amdgcn_mfma_f32_16x16x32_bf16(afp[1][ks], bfr, acc1, 0,0,0);
    }
    float* op = out + ((size_t)b*64 + t*16 + m) * DIM;
    *(float4*)(op + (h*2+0)*16 + qd*4) =
        make_float4(acc0[0]+bvp[0][0], acc0[1]+bvp[0][1], acc0[2]+bvp[0][2], acc0[3]+bvp[0][3]);
    *(float4*)(op + (h*2+1)*16 + qd*4) =
        make_float4(acc1[0]+bvp[1][0], acc1[1]+bvp[1][1], acc1[2]+bvp[1][2], acc1[3]+bvp[1][3]);
  }
}

extern "C" void kernel_launch(void* const* d_in, const int* in_sizes, int n_in,
                              void* d_out, int out_size, void* d_ws, size_t ws_size,
                              hipStream_t stream) {
  const float* x    = (const float*)d_in[0];
  const float* mask = (const float*)d_in[1];
  const float* rpb  = (const float*)d_in[2];
  const int*   ridx = (const int*)d_in[3];
  const float* w1   = (const float*)d_in[4];
  const float* b1   = (const float*)d_in[5];
  const float* w2   = (const float*)d_in[6];
  const float* qkvw = (const float*)d_in[7];
  const float* qkvb = (const float*)d_in[8];
  const float* pw   = (const float*)d_in[9];
  const float* pb   = (const float*)d_in[10];
  const float* ls   = (const float*)d_in[11];
  float* out = (float*)d_out;

  char* ws = (char*)d_ws;
  float* btab = (float*)(ws);                       // 16 KB slot
  float* bmt  = (float*)(ws + 16384);               // 6,291,456 B
  u32* wq = (u32*)(ws + 16384 + 6291456);           // 221,184 B
  u32* wp = (u32*)(ws + 16384 + 6291456 + 221184);  // 73,728 B
  // total ws use: ~6.6 MB

  k_cpb1<<<TBL, 64, 0, stream>>>(rpb, w1, b1, w2, btab);
  k_wcvt<<<(73728 + 255) / 256, 256, 0, stream>>>(qkvw, pw, wq, wp);
  k_bmt<<<(NW * HEADS * 4096 + 255) / 256, 256, 0, stream>>>(btab, ridx, mask, bmt);
  k_mega<<<BATCH, 384, 0, stream>>>(x, wq, qkvb, bmt, ls, wp, pb, out);
}